// Round 7
// baseline (608.543 us; speedup 1.0000x reference)
//
#include <hip/hip_runtime.h>
#include <math.h>

#define NQ 100
#define MM 400
#define DD 512
#define KK 10
#define NS 20           // screened candidates per row (true top-10 must be subset)

typedef short v8s __attribute__((ext_vector_type(8)));   // 8 bf16 (4 VGPRs)
typedef float v4f __attribute__((ext_vector_type(4)));   // 4 f32 acc

// ---- NEW-path workspace byte offsets ----
#define NOFF_S     81920000UL
#define NOFF_XB   145920000UL
#define NOFF_IDX  186880000UL
#define NOFF_VALS 190080000UL
#define NOFF_I10  193280000UL
#define NOFF_RES  194880000UL
#define NEED_NEW  195200000UL

// ---- OLD-path (fallback) offsets ----
#define OOFF_IDX16 81920000UL
#define OOFF_VALSD 84480000UL
#define OOFF_IDX10 87680000UL
#define OOFF_RESD  89280000UL

static __device__ __forceinline__ unsigned short f2bf(float x) {
  unsigned u = __float_as_uint(x);
  unsigned r = (u + 0x7FFFu + ((u >> 16) & 1u)) >> 16;   // RNE; inputs have no NaN
  return (unsigned short)r;
}

// ---------------------------------------------------------------------------
// K1: gather Xs[q][m][:] = X[ranks[m][q]][:]  (f32) + bf16 copy for MFMA screen
// ---------------------------------------------------------------------------
__global__ void k_gather(const float* __restrict__ X, const int* __restrict__ ranks,
                         float* __restrict__ Xs, unsigned short* __restrict__ Xsb,
                         int make_bf) {
  int gid = blockIdx.x * 256 + threadIdx.x;        // 5,120,000 threads exactly
  int c4  = gid & 127;
  int row = gid >> 7;                              // q*MM + m
  int q   = row / MM;
  int m   = row - q * MM;
  int id  = ranks[m * NQ + q];
  float4 v = ((const float4*)X)[(size_t)id * 128 + c4];
  ((float4*)Xs)[(size_t)row * 128 + c4] = v;
  if (make_bf) {
    ushort4 h;
    h.x = f2bf(v.x); h.y = f2bf(v.y); h.z = f2bf(v.z); h.w = f2bf(v.w);
    ((ushort4*)Xsb)[(size_t)row * 128 + c4] = h;
  }
}

// ---------------------------------------------------------------------------
// K2: bf16 MFMA screening GEMM  S = Xs Xs^T per query, S materialized f32.
// ---------------------------------------------------------------------------
#define LDB 40
__launch_bounds__(256)
__global__ void k_gemm(const unsigned short* __restrict__ Xsb, float* __restrict__ S) {
  __shared__ unsigned short As[128 * LDB];
  __shared__ unsigned short Bs[128 * LDB];

  const int q    = blockIdx.y;
  const int mt   = blockIdx.x >> 2;
  const int nt   = blockIdx.x & 3;
  const int m0   = mt * 128, n0 = nt * 128;
  const int tid  = threadIdx.x;
  const int wave = tid >> 6, lane = tid & 63;
  const int wr   = wave >> 1, wc = wave & 1;       // wave origin in block tile
  const int frow = lane & 15, quad = lane >> 4;

  const unsigned short* Xq = Xsb + (size_t)q * MM * DD;

  v4f acc[4][4];
  #pragma unroll
  for (int i = 0; i < 4; ++i)
    #pragma unroll
    for (int j = 0; j < 4; ++j)
      acc[i][j] = (v4f){0.f, 0.f, 0.f, 0.f};

  const int sr = tid >> 1;                 // staging row 0..127
  const int sk = (tid & 1) * 16;           // staging k-half

  for (int kc = 0; kc < DD; kc += 32) {
    __syncthreads();
    {  // stage A rows (m-block)
      int mrow = m0 + sr; if (mrow > MM - 1) mrow = MM - 1;
      const unsigned short* src = Xq + (size_t)mrow * DD + kc + sk;
      v8s t0 = *(const v8s*)(src);
      v8s t1 = *(const v8s*)(src + 8);
      *(v8s*)&As[sr * LDB + sk]     = t0;
      *(v8s*)&As[sr * LDB + sk + 8] = t1;
    }
    {  // stage B rows (n-block)
      int nrow = n0 + sr; if (nrow > MM - 1) nrow = MM - 1;
      const unsigned short* src = Xq + (size_t)nrow * DD + kc + sk;
      v8s t0 = *(const v8s*)(src);
      v8s t1 = *(const v8s*)(src + 8);
      *(v8s*)&Bs[sr * LDB + sk]     = t0;
      *(v8s*)&Bs[sr * LDB + sk + 8] = t1;
    }
    __syncthreads();

    v8s a[4], b[4];
    #pragma unroll
    for (int i = 0; i < 4; ++i)
      a[i] = *(const v8s*)&As[(wr * 64 + i * 16 + frow) * LDB + quad * 8];
    #pragma unroll
    for (int j = 0; j < 4; ++j)
      b[j] = *(const v8s*)&Bs[(wc * 64 + j * 16 + frow) * LDB + quad * 8];
    #pragma unroll
    for (int i = 0; i < 4; ++i)
      #pragma unroll
      for (int j = 0; j < 4; ++j)
        acc[i][j] = __builtin_amdgcn_mfma_f32_16x16x32_bf16(a[i], b[j], acc[i][j], 0, 0, 0);
  }

  // epilogue: C layout col=lane&15, row=quad*4+reg  [m89-verified]
  #pragma unroll
  for (int j = 0; j < 4; ++j) {
    int n = n0 + wc * 64 + j * 16 + frow;
    if (n >= MM) continue;
    #pragma unroll
    for (int i = 0; i < 4; ++i) {
      #pragma unroll
      for (int r = 0; r < 4; ++r) {
        int m = m0 + wr * 64 + i * 16 + quad * 4 + r;
        if (m < MM) S[((size_t)q * MM + m) * MM + n] = acc[i][j][r];
      }
    }
  }
}

// ---------------------------------------------------------------------------
// K3 fused, 2 ROWS PER WAVE: two independent selection butterflies interleave
// per iteration (row B's VALU hides row A's shuffle latency), two refine-dot
// streams interleave in phase 2, rank runs both rows in parallel lane groups.
// Same total work, ~2x ILP at constant residency.
//   - selection bit-identical per row to old k_topk (key pack, order, ties).
//   - refine / rank / dba / res_top numerics bit-identical to round 5
//     (a[] kept as f32; f32->f64 conversion is exact, so each product is the
//      same f64 value as before).
//   - winner indices go through LDS si[][] with a __syncthreads() before any
//     read; values clamped (hardening, no-op).
//   - XCD-chunked block->row map keeps each query's rows on one XCD.
// ---------------------------------------------------------------------------
__launch_bounds__(256)
__global__ void k_srdba(const float* __restrict__ Xs, const float* __restrict__ Q,
                        const float* __restrict__ S,
                        float* __restrict__ out_x, float* __restrict__ out_rt,
                        double* __restrict__ resd) {
  const int wv   = threadIdx.x >> 6;
  const int lane = threadIdx.x & 63;
  const int b    = blockIdx.x;                   // 5000 blocks
  const int cb   = (b & 7) * 625 + (b >> 3);     // 5000 = 8*625, bijective
  const int rb0  = wv * 2;                       // row-in-block base (0,2,4,6)
  const int row0 = cb * 8 + rb0;                 // 8 rows/block, 8 | 400: one q
  const int q    = row0 / MM;
  const float* Xq = Xs + (size_t)q * MM * DD;

  // monotone keys over the two S rows (identical per row to old k_topk)
  unsigned long long key[2][7];
  #pragma unroll
  for (int r = 0; r < 2; ++r) {
    const float* Sr = S + (size_t)(row0 + r) * MM;
    #pragma unroll
    for (int s = 0; s < 7; ++s) {
      int n = lane + 64 * s;
      if (n < MM) {
        unsigned u = __float_as_uint(Sr[n]);
        u ^= (u >> 31) ? 0xFFFFFFFFu : 0x80000000u;        // monotone map
        key[r][s] = ((unsigned long long)u << 32) | (unsigned long long)(0xFFFFFFFFu - (unsigned)n);
      } else {
        key[r][s] = 0ull;
      }
    }
  }

  __shared__ double sv[8][NS];
  __shared__ int    si[8][NS];
  __shared__ double tv[8][KK];
  __shared__ int    ti[8][KK];

  // ---- PHASE 1: two interleaved selections; winner indices -> LDS ----
  #pragma unroll
  for (int t = 0; t < NS; ++t) {
    #pragma unroll
    for (int r = 0; r < 2; ++r) {
      unsigned long long w = key[r][0];
      #pragma unroll
      for (int s = 1; s < 7; ++s) w = (key[r][s] > w) ? key[r][s] : w;
      #pragma unroll
      for (int off = 32; off; off >>= 1) {
        unsigned long long o = __shfl_xor(w, off);
        w = (o > w) ? o : w;
      }
      #pragma unroll
      for (int s = 0; s < 7; ++s)
        if (key[r][s] == w) key[r][s] = 0ull;
      int n = (int)(0xFFFFFFFFu - (unsigned)(w & 0xFFFFFFFFull)); // uniform
      n = (n < 0) ? 0 : ((n > MM - 1) ? MM - 1 : n);              // hardening
      if (lane == 0) si[rb0 + r][t] = n;
    }
  }
  __syncthreads();   // si visible (and ordered) for all lanes

  // own descriptors, f32 (exact; converted at use)
  float a[2][8];
  #pragma unroll
  for (int r = 0; r < 2; ++r) {
    int m = (row0 + r) - q * MM;
    const float* ar = Xq + (size_t)m * DD + lane * 8;
    float4 a0 = *(const float4*)(ar);
    float4 a1 = *(const float4*)(ar + 4);
    a[r][0]=a0.x; a[r][1]=a0.y; a[r][2]=a0.z; a[r][3]=a0.w;
    a[r][4]=a1.x; a[r][5]=a1.y; a[r][6]=a1.z; a[r][7]=a1.w;
  }

  // ---- PHASE 2: 40 refine dots, indices known up front (full MLP) ----
  #pragma unroll
  for (int t = 0; t < NS; ++t) {
    #pragma unroll
    for (int r = 0; r < 2; ++r) {
      int n = si[rb0 + r][t];
      const float* br = Xq + (size_t)n * DD + lane * 8;
      float4 b0 = *(const float4*)(br);
      float4 b1 = *(const float4*)(br + 4);
      double dp = (double)a[r][0]*(double)b0.x + (double)a[r][1]*(double)b0.y
                + (double)a[r][2]*(double)b0.z + (double)a[r][3]*(double)b0.w
                + (double)a[r][4]*(double)b1.x + (double)a[r][5]*(double)b1.y
                + (double)a[r][6]*(double)b1.z + (double)a[r][7]*(double)b1.w;
      #pragma unroll
      for (int off = 32; off; off >>= 1) dp += __shfl_xor(dp, off);
      if (lane == 0) sv[rb0 + r][t] = dp;
    }
  }
  __syncthreads();

  // exact rank among NS refined values, both rows in parallel lane groups
  {
    const int rr = lane >> 5;          // 0: row A (lanes 0-31), 1: row B
    const int l  = lane & 31;
    if (l < NS) {
      const int rb = rb0 + rr;
      double v = sv[rb][l]; int n = si[rb][l];
      int rank = 0;
      #pragma unroll
      for (int i = 0; i < NS; ++i)
        rank += (sv[rb][i] > v) || (sv[rb][i] == v && si[rb][i] < n);
      if (rank < KK) { tv[rb][rank] = v; ti[rb][rank] = n; }
    }
  }
  __syncthreads();

  // dba + res_top per row (rows sequential; loads within a row independent).
  // Same accumulation order and /denom as round 5.
  #pragma unroll
  for (int r = 0; r < 2; ++r) {
    const int rb  = rb0 + r;
    const int row = row0 + r;
    double acc[8] = {0,0,0,0,0,0,0,0};
    double denom = 0.0;
    #pragma unroll
    for (int k = 0; k < KK; ++k) {
      double vv = tv[rb][k];
      double wk = (k == 0) ? 1.0 : 0.15 * vv;
      denom += wk;
      const float* gr = Xq + (size_t)ti[rb][k] * DD + lane * 8;
      float4 g0 = *(const float4*)(gr);
      float4 g1 = *(const float4*)(gr + 4);
      acc[0] += wk * (double)g0.x; acc[1] += wk * (double)g0.y;
      acc[2] += wk * (double)g0.z; acc[3] += wk * (double)g0.w;
      acc[4] += wk * (double)g1.x; acc[5] += wk * (double)g1.y;
      acc[6] += wk * (double)g1.z; acc[7] += wk * (double)g1.w;
    }
    double x[8];
    #pragma unroll
    for (int e = 0; e < 8; ++e) x[e] = acc[e] / denom;

    float* ox = out_x + (size_t)row * DD + lane * 8;
    *(float4*)(ox)     = make_float4((float)x[0], (float)x[1], (float)x[2], (float)x[3]);
    *(float4*)(ox + 4) = make_float4((float)x[4], (float)x[5], (float)x[6], (float)x[7]);

    const float* Qr = Q + (size_t)q * DD + lane * 8;
    float4 q0 = *(const float4*)(Qr);
    float4 q1 = *(const float4*)(Qr + 4);
    double pp = x[0]*(double)q0.x + x[1]*(double)q0.y + x[2]*(double)q0.z + x[3]*(double)q0.w
              + x[4]*(double)q1.x + x[5]*(double)q1.y + x[6]*(double)q1.z + x[7]*(double)q1.w;
    #pragma unroll
    for (int off = 32; off; off >>= 1) pp += __shfl_xor(pp, off);
    if (lane == 0) { resd[row] = pp; out_rt[row] = (float)pp; }
  }
}

// ---------------------------------------------------------------------------
// OLD K2 (fallback if ws too small): f32 tile GEMM + fused top-16
// ---------------------------------------------------------------------------
#define TM 32
#define TN 128
#define KC 16
__launch_bounds__(256, 2)
__global__ void k_score_top16(const float* __restrict__ Xs, int* __restrict__ idx16) {
  __shared__ float As_[KC][TM];
  __shared__ float Bs_[KC][TN];
  __shared__ float Cs_[TM][408];
  const int q   = blockIdx.y;
  const int m0  = blockIdx.x * TM;
  const int tid = threadIdx.x;
  const int tr  = tid & 7;
  const int tc  = tid >> 3;
  const float* Xq = Xs + (size_t)q * MM * DD;
  for (int nt = 0; nt < 4; ++nt) {
    const int n0 = nt * TN;
    float acc[4][4] = {{0.f,0.f,0.f,0.f},{0.f,0.f,0.f,0.f},
                       {0.f,0.f,0.f,0.f},{0.f,0.f,0.f,0.f}};
    for (int kc = 0; kc < DD; kc += KC) {
      __syncthreads();
      { int r = tid >> 3; int cc = (tid & 7) * 2;
        int mrow = m0 + r; if (mrow > MM - 1) mrow = MM - 1;
        float2 a = *(const float2*)(Xq + (size_t)mrow * DD + kc + cc);
        As_[cc + 0][r] = a.x; As_[cc + 1][r] = a.y; }
      { int r = tid >> 1; int cc = (tid & 1) * 8;
        int nrow = n0 + r; if (nrow > MM - 1) nrow = MM - 1;
        const float* src = Xq + (size_t)nrow * DD + kc + cc;
        #pragma unroll
        for (int j = 0; j < 2; ++j) {
          float4 b = *(const float4*)(src + 4 * j);
          Bs_[cc + 4*j + 0][r] = b.x; Bs_[cc + 4*j + 1][r] = b.y;
          Bs_[cc + 4*j + 2][r] = b.z; Bs_[cc + 4*j + 3][r] = b.w; } }
      __syncthreads();
      #pragma unroll
      for (int k = 0; k < KC; ++k) {
        float4 a4 = *(const float4*)&As_[k][tr * 4];
        float4 b4 = *(const float4*)&Bs_[k][tc * 4];
        float av[4] = {a4.x, a4.y, a4.z, a4.w};
        float bw[4] = {b4.x, b4.y, b4.z, b4.w};
        #pragma unroll
        for (int i = 0; i < 4; ++i)
          #pragma unroll
          for (int j = 0; j < 4; ++j)
            acc[i][j] = fmaf(av[i], bw[j], acc[i][j]);
      }
    }
    #pragma unroll
    for (int i = 0; i < 4; ++i) {
      int r = tr * 4 + i;
      #pragma unroll
      for (int j = 0; j < 4; ++j) {
        int col = n0 + tc * 4 + j;
        if (col < MM) Cs_[r][col] = acc[i][j];
      }
    }
  }
  __syncthreads();
  const int lane = tid & 63;
  const int wv   = tid >> 6;
  for (int r = wv; r < TM; r += 4) {
    const int m = m0 + r;
    if (m >= MM) continue;
    float v[7]; int nn[7];
    #pragma unroll
    for (int s = 0; s < 7; ++s) {
      int n = lane + 64 * s;
      bool ok = (n < MM);
      v[s]  = ok ? Cs_[r][n] : -INFINITY;
      nn[s] = ok ? n : 0x7fffffff;
    }
    for (int t = 0; t < 16; ++t) {
      float bv = v[0]; int bn = nn[0];
      #pragma unroll
      for (int s = 1; s < 7; ++s)
        if (v[s] > bv || (v[s] == bv && nn[s] < bn)) { bv = v[s]; bn = nn[s]; }
      for (int off = 32; off; off >>= 1) {
        float ov = __shfl_xor(bv, off);
        int   on = __shfl_xor(bn, off);
        if (ov > bv || (ov == bv && on < bn)) { bv = ov; bn = on; }
      }
      if (lane == 0) idx16[((size_t)q * MM + m) * 16 + t] = bn;
      #pragma unroll
      for (int s = 0; s < 7; ++s)
        if (nn[s] == bn) v[s] = -INFINITY;
    }
  }
}

// ---------------------------------------------------------------------------
// OLD K3: refine (fallback path)
// ---------------------------------------------------------------------------
__global__ void k_refine(const float* __restrict__ Xs, const int* __restrict__ idxbuf,
                         int ns, double* __restrict__ valsd, int* __restrict__ idx10) {
  const int row  = blockIdx.x;           // q*MM + m
  const int q    = row / MM;
  const int m    = row - q * MM;
  const int lane = threadIdx.x;          // 64
  const float* Xq = Xs + (size_t)q * MM * DD;

  double a[8];
  {
    const float* ar = Xq + (size_t)m * DD + lane * 8;
    float4 a0 = *(const float4*)(ar);
    float4 a1 = *(const float4*)(ar + 4);
    a[0]=a0.x; a[1]=a0.y; a[2]=a0.z; a[3]=a0.w;
    a[4]=a1.x; a[5]=a1.y; a[6]=a1.z; a[7]=a1.w;
  }
  __shared__ double sv[24];
  __shared__ int    si[24];
  for (int j = 0; j < ns; ++j) {
    int n = idxbuf[(size_t)row * ns + j];
    const float* br = Xq + (size_t)n * DD + lane * 8;
    float4 b0 = *(const float4*)(br);
    float4 b1 = *(const float4*)(br + 4);
    double s = a[0]*(double)b0.x + a[1]*(double)b0.y + a[2]*(double)b0.z + a[3]*(double)b0.w
             + a[4]*(double)b1.x + a[5]*(double)b1.y + a[6]*(double)b1.z + a[7]*(double)b1.w;
    for (int off = 32; off; off >>= 1) s += __shfl_xor(s, off);
    if (lane == 0) { sv[j] = s; si[j] = n; }
  }
  __syncthreads();
  if (lane < ns) {
    double v = sv[lane]; int n = si[lane];
    int rank = 0;
    for (int i = 0; i < ns; ++i)
      if (sv[i] > v || (sv[i] == v && si[i] < n)) ++rank;
    if (rank < KK) {
      valsd[(size_t)row * KK + rank] = v;
      idx10[(size_t)row * KK + rank] = n;
    }
  }
}

// ---------------------------------------------------------------------------
// OLD K4: x_dba + res_top (fallback path)
// ---------------------------------------------------------------------------
__global__ void k_dba(const float* __restrict__ Xs, const float* __restrict__ Q,
                      const double* __restrict__ valsd, const int* __restrict__ idx10,
                      float* __restrict__ out_x, float* __restrict__ out_rt,
                      double* __restrict__ resd) {
  const int row = blockIdx.x;            // q*MM + m
  const int q   = row / MM;
  const int tid = threadIdx.x;           // 128
  const float* Xq = Xs + (size_t)q * MM * DD;

  double w[KK]; int id[KK]; double denom = 0.0;
  #pragma unroll
  for (int k = 0; k < KK; ++k) {
    double vv = valsd[(size_t)row * KK + k];
    w[k] = (k == 0) ? 1.0 : 0.15 * vv;
    denom += w[k];
    id[k] = idx10[(size_t)row * KK + k];
  }
  double acc0 = 0, acc1 = 0, acc2 = 0, acc3 = 0;
  #pragma unroll
  for (int k = 0; k < KK; ++k) {
    float4 g = *(const float4*)(Xq + (size_t)id[k] * DD + tid * 4);
    acc0 += w[k] * (double)g.x;
    acc1 += w[k] * (double)g.y;
    acc2 += w[k] * (double)g.z;
    acc3 += w[k] * (double)g.w;
  }
  double x0 = acc0 / denom, x1 = acc1 / denom, x2 = acc2 / denom, x3 = acc3 / denom;
  ((float4*)out_x)[(size_t)row * 128 + tid] =
      make_float4((float)x0, (float)x1, (float)x2, (float)x3);

  const float* Qr = Q + (size_t)q * DD + tid * 4;
  double p = x0 * (double)Qr[0] + x1 * (double)Qr[1] + x2 * (double)Qr[2] + x3 * (double)Qr[3];
  for (int off = 32; off; off >>= 1) p += __shfl_xor(p, off);
  __shared__ double ps[2];
  if ((tid & 63) == 0) ps[tid >> 6] = p;
  __syncthreads();
  if (tid == 0) {
    double rt = ps[0] + ps[1];
    resd[row]   = rt;
    out_rt[row] = (float)rt;
  }
}

// ---------------------------------------------------------------------------
// K5: stable descending argsort of res_top (f64) per query → pre, rerank_final
// ---------------------------------------------------------------------------
__global__ void k_sort(const double* __restrict__ resd, const int* __restrict__ ranks,
                       float* __restrict__ out_rr, float* __restrict__ out_pre) {
  const int q   = blockIdx.x;
  const int tid = threadIdx.x;           // 512
  __shared__ double sv[MM];
  if (tid < MM) sv[tid] = resd[(size_t)q * MM + tid];
  __syncthreads();
  if (tid < MM) {
    double v = sv[tid];
    int rank = 0;
    for (int j = 0; j < MM; ++j) {
      double u = sv[j];
      rank += (u > v) || (u == v && j < tid);
    }
    out_pre[(size_t)q * MM + rank] = (float)tid;
    out_rr [(size_t)q * MM + rank] = (float)ranks[tid * NQ + q];
  }
}

// ---------------------------------------------------------------------------
extern "C" void kernel_launch(void* const* d_in, const int* in_sizes, int n_in,
                              void* d_out, int out_size, void* d_ws, size_t ws_size,
                              hipStream_t stream) {
  const float* X     = (const float*)d_in[0];
  const float* Q     = (const float*)d_in[1];
  const int*   ranks = (const int*)d_in[2];

  float* out    = (float*)d_out;
  float* out_rr = out;                   // rerank_final [100][400]
  float* out_rt = out + 40000;           // res_top      [100][400]
  float* out_pr = out + 80000;           // pre          [100][400]
  float* out_x  = out + 120000;          // x_dba        [100][400][512]

  float* Xs = (float*)d_ws;

  if (ws_size >= NEED_NEW) {
    float*          S     = (float*)          ((char*)d_ws + NOFF_S);
    unsigned short* Xsb   = (unsigned short*) ((char*)d_ws + NOFF_XB);
    double*         resd  = (double*)         ((char*)d_ws + NOFF_RES);

    k_gather<<<dim3(20000),   dim3(256), 0, stream>>>(X, ranks, Xs, Xsb, 1);
    k_gemm  <<<dim3(16, 100), dim3(256), 0, stream>>>(Xsb, S);
    k_srdba <<<dim3(5000),    dim3(256), 0, stream>>>(Xs, Q, S, out_x, out_rt, resd);
    k_sort  <<<dim3(100),     dim3(512), 0, stream>>>(resd, ranks, out_rr, out_pr);
  } else {
    int*    idx16 = (int*)   ((char*)d_ws + OOFF_IDX16);
    double* valsd = (double*)((char*)d_ws + OOFF_VALSD);
    int*    idx10 = (int*)   ((char*)d_ws + OOFF_IDX10);
    double* resd  = (double*)((char*)d_ws + OOFF_RESD);

    k_gather     <<<dim3(20000),   dim3(256), 0, stream>>>(X, ranks, Xs, (unsigned short*)0, 0);
    k_score_top16<<<dim3(13, 100), dim3(256), 0, stream>>>(Xs, idx16);
    k_refine     <<<dim3(40000),   dim3(64),  0, stream>>>(Xs, idx16, 16, valsd, idx10);
    k_dba        <<<dim3(40000),   dim3(128), 0, stream>>>(Xs, Q, valsd, idx10, out_x, out_rt, resd);
    k_sort       <<<dim3(100),     dim3(512), 0, stream>>>(resd, ranks, out_rr, out_pr);
  }
}

// Round 8
// 485.933 us; speedup vs baseline: 1.2523x; 1.2523x over previous
//
#include <hip/hip_runtime.h>
#include <math.h>

#define NQ 100
#define MM 400
#define DD 512
#define KK 10
#define NS 20           // screened candidates per row (true top-10 must be subset)

typedef short v8s __attribute__((ext_vector_type(8)));   // 8 bf16 (4 VGPRs)
typedef float v4f __attribute__((ext_vector_type(4)));   // 4 f32 acc

// ---- NEW-path workspace byte offsets ----
#define NOFF_S     81920000UL
#define NOFF_XB   145920000UL
#define NOFF_IDX  186880000UL
#define NOFF_VALS 190080000UL
#define NOFF_I10  193280000UL
#define NOFF_RES  194880000UL
#define NEED_NEW  195200000UL

// ---- OLD-path (fallback) offsets ----
#define OOFF_IDX16 81920000UL
#define OOFF_VALSD 84480000UL
#define OOFF_IDX10 87680000UL
#define OOFF_RESD  89280000UL

static __device__ __forceinline__ unsigned short f2bf(float x) {
  unsigned u = __float_as_uint(x);
  unsigned r = (u + 0x7FFFu + ((u >> 16) & 1u)) >> 16;   // RNE; inputs have no NaN
  return (unsigned short)r;
}

// ---------------------------------------------------------------------------
// K1: gather Xs[q][m][:] = X[ranks[m][q]][:]  (f32) + bf16 copy for MFMA screen
// ---------------------------------------------------------------------------
__global__ void k_gather(const float* __restrict__ X, const int* __restrict__ ranks,
                         float* __restrict__ Xs, unsigned short* __restrict__ Xsb,
                         int make_bf) {
  int gid = blockIdx.x * 256 + threadIdx.x;        // 5,120,000 threads exactly
  int c4  = gid & 127;
  int row = gid >> 7;                              // q*MM + m
  int q   = row / MM;
  int m   = row - q * MM;
  int id  = ranks[m * NQ + q];
  float4 v = ((const float4*)X)[(size_t)id * 128 + c4];
  ((float4*)Xs)[(size_t)row * 128 + c4] = v;
  if (make_bf) {
    ushort4 h;
    h.x = f2bf(v.x); h.y = f2bf(v.y); h.z = f2bf(v.z); h.w = f2bf(v.w);
    ((ushort4*)Xsb)[(size_t)row * 128 + c4] = h;
  }
}

// ---------------------------------------------------------------------------
// K2: bf16 MFMA screening GEMM  S = Xs Xs^T per query, S materialized f32.
// ---------------------------------------------------------------------------
#define LDB 40
__launch_bounds__(256)
__global__ void k_gemm(const unsigned short* __restrict__ Xsb, float* __restrict__ S) {
  __shared__ unsigned short As[128 * LDB];
  __shared__ unsigned short Bs[128 * LDB];

  const int q    = blockIdx.y;
  const int mt   = blockIdx.x >> 2;
  const int nt   = blockIdx.x & 3;
  const int m0   = mt * 128, n0 = nt * 128;
  const int tid  = threadIdx.x;
  const int wave = tid >> 6, lane = tid & 63;
  const int wr   = wave >> 1, wc = wave & 1;       // wave origin in block tile
  const int frow = lane & 15, quad = lane >> 4;

  const unsigned short* Xq = Xsb + (size_t)q * MM * DD;

  v4f acc[4][4];
  #pragma unroll
  for (int i = 0; i < 4; ++i)
    #pragma unroll
    for (int j = 0; j < 4; ++j)
      acc[i][j] = (v4f){0.f, 0.f, 0.f, 0.f};

  const int sr = tid >> 1;                 // staging row 0..127
  const int sk = (tid & 1) * 16;           // staging k-half

  for (int kc = 0; kc < DD; kc += 32) {
    __syncthreads();
    {  // stage A rows (m-block)
      int mrow = m0 + sr; if (mrow > MM - 1) mrow = MM - 1;
      const unsigned short* src = Xq + (size_t)mrow * DD + kc + sk;
      v8s t0 = *(const v8s*)(src);
      v8s t1 = *(const v8s*)(src + 8);
      *(v8s*)&As[sr * LDB + sk]     = t0;
      *(v8s*)&As[sr * LDB + sk + 8] = t1;
    }
    {  // stage B rows (n-block)
      int nrow = n0 + sr; if (nrow > MM - 1) nrow = MM - 1;
      const unsigned short* src = Xq + (size_t)nrow * DD + kc + sk;
      v8s t0 = *(const v8s*)(src);
      v8s t1 = *(const v8s*)(src + 8);
      *(v8s*)&Bs[sr * LDB + sk]     = t0;
      *(v8s*)&Bs[sr * LDB + sk + 8] = t1;
    }
    __syncthreads();

    v8s a[4], b[4];
    #pragma unroll
    for (int i = 0; i < 4; ++i)
      a[i] = *(const v8s*)&As[(wr * 64 + i * 16 + frow) * LDB + quad * 8];
    #pragma unroll
    for (int j = 0; j < 4; ++j)
      b[j] = *(const v8s*)&Bs[(wc * 64 + j * 16 + frow) * LDB + quad * 8];
    #pragma unroll
    for (int i = 0; i < 4; ++i)
      #pragma unroll
      for (int j = 0; j < 4; ++j)
        acc[i][j] = __builtin_amdgcn_mfma_f32_16x16x32_bf16(a[i], b[j], acc[i][j], 0, 0, 0);
  }

  // epilogue: C layout col=lane&15, row=quad*4+reg  [m89-verified]
  #pragma unroll
  for (int j = 0; j < 4; ++j) {
    int n = n0 + wc * 64 + j * 16 + frow;
    if (n >= MM) continue;
    #pragma unroll
    for (int i = 0; i < 4; ++i) {
      #pragma unroll
      for (int r = 0; r < 4; ++r) {
        int m = m0 + wr * 64 + i * 16 + quad * 4 + r;
        if (m < MM) S[((size_t)q * MM + m) * MM + n] = acc[i][j][r];
      }
    }
  }
}

// ---------------------------------------------------------------------------
// K3 fused (round-8): RADIX-BALLOT top-NS selection — zero DS ops, counts on
// the scalar pipe — then the round-5 refine/rank/dba/res_top unchanged.
//   Selection: T = exact NS-th largest monotone-u32 key via 32-pass MSB
//   binary search (count = Σ s_bcnt1(ballot(kv>=cand))); ballot-compact all
//   entries >= T (C>=NS; ascending index by construction); rank-count among C
//   by (value desc, index asc) == lax.top_k order -> si[rank] bit-identical
//   to the old sequential extraction.
//   Sentinels (n>=MM) get key 0 < every real key <= T: never counted/selected.
//   refine / rank / dba / res_top numerics bit-identical to round 5.
//   XCD-chunked block->row map keeps each query's rows on one XCD.
// ---------------------------------------------------------------------------
__launch_bounds__(256)
__global__ void k_srdba(const float* __restrict__ Xs, const float* __restrict__ Q,
                        const float* __restrict__ S,
                        float* __restrict__ out_x, float* __restrict__ out_rt,
                        double* __restrict__ resd) {
  const int wv   = threadIdx.x >> 6;
  const int lane = threadIdx.x & 63;
  const int b    = blockIdx.x;
  const int cb   = (b & 7) * 1250 + (b >> 3);    // 10000 = 8*1250, bijective
  const int row  = cb * 4 + wv;                  // 400 % 4 == 0: no q-crossing
  const int q    = row / MM;
  const int m    = row - q * MM;
  const float* Xq = Xs + (size_t)q * MM * DD;
  const float* Sr = S  + (size_t)row * MM;

  // own descriptor in f64 (same as round 5)
  double a[8];
  {
    const float* ar = Xq + (size_t)m * DD + lane * 8;
    float4 a0 = *(const float4*)(ar);
    float4 a1 = *(const float4*)(ar + 4);
    a[0]=a0.x; a[1]=a0.y; a[2]=a0.z; a[3]=a0.w;
    a[4]=a1.x; a[5]=a1.y; a[6]=a1.z; a[7]=a1.w;
  }

  // monotone u32 keys over the S row (same map as before; 32-bit now)
  unsigned kv[7];
  #pragma unroll
  for (int s = 0; s < 7; ++s) {
    int n = lane + 64 * s;
    if (n < MM) {
      unsigned u = __float_as_uint(Sr[n]);
      kv[s] = u ^ ((u >> 31) ? 0xFFFFFFFFu : 0x80000000u);   // monotone map
    } else {
      kv[s] = 0u;                                            // below all real keys
    }
  }

  __shared__ double   sv[4][NS];
  __shared__ int      si[4][NS];
  __shared__ double   tv[4][KK];
  __shared__ int      ti[4][KK];
  __shared__ unsigned lv[4][64];
  __shared__ int      li[4][64];

  // ---- PHASE 1a: T = NS-th largest key (32-pass radix search, SALU counts) ----
  unsigned prefix = 0u;
  #pragma unroll
  for (int bit = 31; bit >= 0; --bit) {
    unsigned cand = prefix | (1u << bit);
    int c = 0;
    #pragma unroll
    for (int s = 0; s < 7; ++s)
      c += (int)(__popcll(__ballot(kv[s] >= cand)));
    prefix = (c >= NS) ? cand : prefix;     // c wave-uniform (scalar)
  }
  // prefix == T: largest u32 with count(>=T) >= NS  == the NS-th largest key

  // ---- PHASE 1b: ballot-compact entries >= T (C in [NS, 64], asc index) ----
  int base = 0;
  #pragma unroll
  for (int s = 0; s < 7; ++s) {
    bool p = (kv[s] >= prefix);
    unsigned long long mk = __ballot(p);
    if (p) {
      unsigned lo = (unsigned)(mk & 0xFFFFFFFFull);
      unsigned hi = (unsigned)(mk >> 32);
      int pos = base + (int)__builtin_amdgcn_mbcnt_hi(hi,
                          __builtin_amdgcn_mbcnt_lo(lo, 0u));
      if (pos < 64) { lv[wv][pos] = kv[s]; li[wv][pos] = lane + 64 * s; }
    }
    base += (int)__popcll(mk);
  }
  int C = (base < 64) ? base : 64;          // clamp (pathological ties only)
  __syncthreads();

  // ---- PHASE 1c: rank among C entries; si[rank] = index (lax.top_k order) ----
  if (lane < C) {
    unsigned v = lv[wv][lane]; int n = li[wv][lane];
    int rank = 0;
    for (int i = 0; i < C; ++i)
      rank += (lv[wv][i] > v) || (lv[wv][i] == v && li[wv][i] < n);
    if (rank < NS) si[wv][rank] = n;
  }
  __syncthreads();

  // indices known up front -> all candidate loads independent & hoistable
  int nsel[NS];
  #pragma unroll
  for (int t = 0; t < NS; ++t) nsel[t] = si[wv][t];   // uniform broadcast reads

  // ---- PHASE 2: refine dots with full MLP (round-5 structure) ----
  #pragma unroll
  for (int t = 0; t < NS; ++t) {
    const float* br = Xq + (size_t)nsel[t] * DD + lane * 8;
    float4 b0 = *(const float4*)(br);
    float4 b1 = *(const float4*)(br + 4);
    double dp = a[0]*(double)b0.x + a[1]*(double)b0.y + a[2]*(double)b0.z + a[3]*(double)b0.w
              + a[4]*(double)b1.x + a[5]*(double)b1.y + a[6]*(double)b1.z + a[7]*(double)b1.w;
    #pragma unroll
    for (int off = 32; off; off >>= 1) dp += __shfl_xor(dp, off);
    if (lane == 0) sv[wv][t] = dp;
  }
  __syncthreads();

  // exact rank among the NS refined values (value desc, index asc — lax.top_k)
  if (lane < NS) {
    double v = sv[wv][lane]; int n = si[wv][lane];
    int rank = 0;
    #pragma unroll
    for (int i = 0; i < NS; ++i)
      rank += (sv[wv][i] > v) || (sv[wv][i] == v && si[wv][i] < n);
    if (rank < KK) { tv[wv][rank] = v; ti[wv][rank] = n; }
  }
  __syncthreads();

  // dba: top-10 rows just read by this wave -> L1/L2 hot. Same accumulation
  // order and /denom as round 5.
  double acc[8] = {0,0,0,0,0,0,0,0};
  double denom = 0.0;
  #pragma unroll
  for (int k = 0; k < KK; ++k) {
    double vv = tv[wv][k];
    double wk = (k == 0) ? 1.0 : 0.15 * vv;
    denom += wk;
    const float* gr = Xq + (size_t)ti[wv][k] * DD + lane * 8;
    float4 g0 = *(const float4*)(gr);
    float4 g1 = *(const float4*)(gr + 4);
    acc[0] += wk * (double)g0.x; acc[1] += wk * (double)g0.y;
    acc[2] += wk * (double)g0.z; acc[3] += wk * (double)g0.w;
    acc[4] += wk * (double)g1.x; acc[5] += wk * (double)g1.y;
    acc[6] += wk * (double)g1.z; acc[7] += wk * (double)g1.w;
  }
  double x[8];
  #pragma unroll
  for (int e = 0; e < 8; ++e) x[e] = acc[e] / denom;

  float* ox = out_x + (size_t)row * DD + lane * 8;
  *(float4*)(ox)     = make_float4((float)x[0], (float)x[1], (float)x[2], (float)x[3]);
  *(float4*)(ox + 4) = make_float4((float)x[4], (float)x[5], (float)x[6], (float)x[7]);

  const float* Qr = Q + (size_t)q * DD + lane * 8;
  float4 q0 = *(const float4*)(Qr);
  float4 q1 = *(const float4*)(Qr + 4);
  double pp = x[0]*(double)q0.x + x[1]*(double)q0.y + x[2]*(double)q0.z + x[3]*(double)q0.w
            + x[4]*(double)q1.x + x[5]*(double)q1.y + x[6]*(double)q1.z + x[7]*(double)q1.w;
  #pragma unroll
  for (int off = 32; off; off >>= 1) pp += __shfl_xor(pp, off);
  if (lane == 0) { resd[row] = pp; out_rt[row] = (float)pp; }
}

// ---------------------------------------------------------------------------
// OLD K2 (fallback if ws too small): f32 tile GEMM + fused top-16
// ---------------------------------------------------------------------------
#define TM 32
#define TN 128
#define KC 16
__launch_bounds__(256, 2)
__global__ void k_score_top16(const float* __restrict__ Xs, int* __restrict__ idx16) {
  __shared__ float As_[KC][TM];
  __shared__ float Bs_[KC][TN];
  __shared__ float Cs_[TM][408];
  const int q   = blockIdx.y;
  const int m0  = blockIdx.x * TM;
  const int tid = threadIdx.x;
  const int tr  = tid & 7;
  const int tc  = tid >> 3;
  const float* Xq = Xs + (size_t)q * MM * DD;
  for (int nt = 0; nt < 4; ++nt) {
    const int n0 = nt * TN;
    float acc[4][4] = {{0.f,0.f,0.f,0.f},{0.f,0.f,0.f,0.f},
                       {0.f,0.f,0.f,0.f},{0.f,0.f,0.f,0.f}};
    for (int kc = 0; kc < DD; kc += KC) {
      __syncthreads();
      { int r = tid >> 3; int cc = (tid & 7) * 2;
        int mrow = m0 + r; if (mrow > MM - 1) mrow = MM - 1;
        float2 a = *(const float2*)(Xq + (size_t)mrow * DD + kc + cc);
        As_[cc + 0][r] = a.x; As_[cc + 1][r] = a.y; }
      { int r = tid >> 1; int cc = (tid & 1) * 8;
        int nrow = n0 + r; if (nrow > MM - 1) nrow = MM - 1;
        const float* src = Xq + (size_t)nrow * DD + kc + cc;
        #pragma unroll
        for (int j = 0; j < 2; ++j) {
          float4 b = *(const float4*)(src + 4 * j);
          Bs_[cc + 4*j + 0][r] = b.x; Bs_[cc + 4*j + 1][r] = b.y;
          Bs_[cc + 4*j + 2][r] = b.z; Bs_[cc + 4*j + 3][r] = b.w; } }
      __syncthreads();
      #pragma unroll
      for (int k = 0; k < KC; ++k) {
        float4 a4 = *(const float4*)&As_[k][tr * 4];
        float4 b4 = *(const float4*)&Bs_[k][tc * 4];
        float av[4] = {a4.x, a4.y, a4.z, a4.w};
        float bw[4] = {b4.x, b4.y, b4.z, b4.w};
        #pragma unroll
        for (int i = 0; i < 4; ++i)
          #pragma unroll
          for (int j = 0; j < 4; ++j)
            acc[i][j] = fmaf(av[i], bw[j], acc[i][j]);
      }
    }
    #pragma unroll
    for (int i = 0; i < 4; ++i) {
      int r = tr * 4 + i;
      #pragma unroll
      for (int j = 0; j < 4; ++j) {
        int col = n0 + tc * 4 + j;
        if (col < MM) Cs_[r][col] = acc[i][j];
      }
    }
  }
  __syncthreads();
  const int lane = tid & 63;
  const int wv   = tid >> 6;
  for (int r = wv; r < TM; r += 4) {
    const int m = m0 + r;
    if (m >= MM) continue;
    float v[7]; int nn[7];
    #pragma unroll
    for (int s = 0; s < 7; ++s) {
      int n = lane + 64 * s;
      bool ok = (n < MM);
      v[s]  = ok ? Cs_[r][n] : -INFINITY;
      nn[s] = ok ? n : 0x7fffffff;
    }
    for (int t = 0; t < 16; ++t) {
      float bv = v[0]; int bn = nn[0];
      #pragma unroll
      for (int s = 1; s < 7; ++s)
        if (v[s] > bv || (v[s] == bv && nn[s] < bn)) { bv = v[s]; bn = nn[s]; }
      for (int off = 32; off; off >>= 1) {
        float ov = __shfl_xor(bv, off);
        int   on = __shfl_xor(bn, off);
        if (ov > bv || (ov == bv && on < bn)) { bv = ov; bn = on; }
      }
      if (lane == 0) idx16[((size_t)q * MM + m) * 16 + t] = bn;
      #pragma unroll
      for (int s = 0; s < 7; ++s)
        if (nn[s] == bn) v[s] = -INFINITY;
    }
  }
}

// ---------------------------------------------------------------------------
// OLD K3: refine (fallback path)
// ---------------------------------------------------------------------------
__global__ void k_refine(const float* __restrict__ Xs, const int* __restrict__ idxbuf,
                         int ns, double* __restrict__ valsd, int* __restrict__ idx10) {
  const int row  = blockIdx.x;           // q*MM + m
  const int q    = row / MM;
  const int m    = row - q * MM;
  const int lane = threadIdx.x;          // 64
  const float* Xq = Xs + (size_t)q * MM * DD;

  double a[8];
  {
    const float* ar = Xq + (size_t)m * DD + lane * 8;
    float4 a0 = *(const float4*)(ar);
    float4 a1 = *(const float4*)(ar + 4);
    a[0]=a0.x; a[1]=a0.y; a[2]=a0.z; a[3]=a0.w;
    a[4]=a1.x; a[5]=a1.y; a[6]=a1.z; a[7]=a1.w;
  }
  __shared__ double sv[24];
  __shared__ int    si[24];
  for (int j = 0; j < ns; ++j) {
    int n = idxbuf[(size_t)row * ns + j];
    const float* br = Xq + (size_t)n * DD + lane * 8;
    float4 b0 = *(const float4*)(br);
    float4 b1 = *(const float4*)(br + 4);
    double s = a[0]*(double)b0.x + a[1]*(double)b0.y + a[2]*(double)b0.z + a[3]*(double)b0.w
             + a[4]*(double)b1.x + a[5]*(double)b1.y + a[6]*(double)b1.z + a[7]*(double)b1.w;
    for (int off = 32; off; off >>= 1) s += __shfl_xor(s, off);
    if (lane == 0) { sv[j] = s; si[j] = n; }
  }
  __syncthreads();
  if (lane < ns) {
    double v = sv[lane]; int n = si[lane];
    int rank = 0;
    for (int i = 0; i < ns; ++i)
      if (sv[i] > v || (sv[i] == v && si[i] < n)) ++rank;
    if (rank < KK) {
      valsd[(size_t)row * KK + rank] = v;
      idx10[(size_t)row * KK + rank] = n;
    }
  }
}

// ---------------------------------------------------------------------------
// OLD K4: x_dba + res_top (fallback path)
// ---------------------------------------------------------------------------
__global__ void k_dba(const float* __restrict__ Xs, const float* __restrict__ Q,
                      const double* __restrict__ valsd, const int* __restrict__ idx10,
                      float* __restrict__ out_x, float* __restrict__ out_rt,
                      double* __restrict__ resd) {
  const int row = blockIdx.x;            // q*MM + m
  const int q   = row / MM;
  const int tid = threadIdx.x;           // 128
  const float* Xq = Xs + (size_t)q * MM * DD;

  double w[KK]; int id[KK]; double denom = 0.0;
  #pragma unroll
  for (int k = 0; k < KK; ++k) {
    double vv = valsd[(size_t)row * KK + k];
    w[k] = (k == 0) ? 1.0 : 0.15 * vv;
    denom += w[k];
    id[k] = idx10[(size_t)row * KK + k];
  }
  double acc0 = 0, acc1 = 0, acc2 = 0, acc3 = 0;
  #pragma unroll
  for (int k = 0; k < KK; ++k) {
    float4 g = *(const float4*)(Xq + (size_t)id[k] * DD + tid * 4);
    acc0 += w[k] * (double)g.x;
    acc1 += w[k] * (double)g.y;
    acc2 += w[k] * (double)g.z;
    acc3 += w[k] * (double)g.w;
  }
  double x0 = acc0 / denom, x1 = acc1 / denom, x2 = acc2 / denom, x3 = acc3 / denom;
  ((float4*)out_x)[(size_t)row * 128 + tid] =
      make_float4((float)x0, (float)x1, (float)x2, (float)x3);

  const float* Qr = Q + (size_t)q * DD + tid * 4;
  double p = x0 * (double)Qr[0] + x1 * (double)Qr[1] + x2 * (double)Qr[2] + x3 * (double)Qr[3];
  for (int off = 32; off; off >>= 1) p += __shfl_xor(p, off);
  __shared__ double ps[2];
  if ((tid & 63) == 0) ps[tid >> 6] = p;
  __syncthreads();
  if (tid == 0) {
    double rt = ps[0] + ps[1];
    resd[row]   = rt;
    out_rt[row] = (float)rt;
  }
}

// ---------------------------------------------------------------------------
// K5: stable descending argsort of res_top (f64) per query → pre, rerank_final
// ---------------------------------------------------------------------------
__global__ void k_sort(const double* __restrict__ resd, const int* __restrict__ ranks,
                       float* __restrict__ out_rr, float* __restrict__ out_pre) {
  const int q   = blockIdx.x;
  const int tid = threadIdx.x;           // 512
  __shared__ double sv[MM];
  if (tid < MM) sv[tid] = resd[(size_t)q * MM + tid];
  __syncthreads();
  if (tid < MM) {
    double v = sv[tid];
    int rank = 0;
    for (int j = 0; j < MM; ++j) {
      double u = sv[j];
      rank += (u > v) || (u == v && j < tid);
    }
    out_pre[(size_t)q * MM + rank] = (float)tid;
    out_rr [(size_t)q * MM + rank] = (float)ranks[tid * NQ + q];
  }
}

// ---------------------------------------------------------------------------
extern "C" void kernel_launch(void* const* d_in, const int* in_sizes, int n_in,
                              void* d_out, int out_size, void* d_ws, size_t ws_size,
                              hipStream_t stream) {
  const float* X     = (const float*)d_in[0];
  const float* Q     = (const float*)d_in[1];
  const int*   ranks = (const int*)d_in[2];

  float* out    = (float*)d_out;
  float* out_rr = out;                   // rerank_final [100][400]
  float* out_rt = out + 40000;           // res_top      [100][400]
  float* out_pr = out + 80000;           // pre          [100][400]
  float* out_x  = out + 120000;          // x_dba        [100][400][512]

  float* Xs = (float*)d_ws;

  if (ws_size >= NEED_NEW) {
    float*          S     = (float*)          ((char*)d_ws + NOFF_S);
    unsigned short* Xsb   = (unsigned short*) ((char*)d_ws + NOFF_XB);
    double*         resd  = (double*)         ((char*)d_ws + NOFF_RES);

    k_gather<<<dim3(20000),   dim3(256), 0, stream>>>(X, ranks, Xs, Xsb, 1);
    k_gemm  <<<dim3(16, 100), dim3(256), 0, stream>>>(Xsb, S);
    k_srdba <<<dim3(10000),   dim3(256), 0, stream>>>(Xs, Q, S, out_x, out_rt, resd);
    k_sort  <<<dim3(100),     dim3(512), 0, stream>>>(resd, ranks, out_rr, out_pr);
  } else {
    int*    idx16 = (int*)   ((char*)d_ws + OOFF_IDX16);
    double* valsd = (double*)((char*)d_ws + OOFF_VALSD);
    int*    idx10 = (int*)   ((char*)d_ws + OOFF_IDX10);
    double* resd  = (double*)((char*)d_ws + OOFF_RESD);

    k_gather     <<<dim3(20000),   dim3(256), 0, stream>>>(X, ranks, Xs, (unsigned short*)0, 0);
    k_score_top16<<<dim3(13, 100), dim3(256), 0, stream>>>(Xs, idx16);
    k_refine     <<<dim3(40000),   dim3(64),  0, stream>>>(Xs, idx16, 16, valsd, idx10);
    k_dba        <<<dim3(40000),   dim3(128), 0, stream>>>(Xs, Q, valsd, idx10, out_x, out_rt, resd);
    k_sort       <<<dim3(100),     dim3(512), 0, stream>>>(resd, ranks, out_rr, out_pr);
  }
}

// Round 9
// 468.485 us; speedup vs baseline: 1.2990x; 1.0372x over previous
//
#include <hip/hip_runtime.h>
#include <math.h>

#define NQ 100
#define MM 400
#define DD 512
#define KK 10
#define NS 20           // screened candidates per row (true top-10 must be subset)

typedef short v8s __attribute__((ext_vector_type(8)));   // 8 bf16 (4 VGPRs)
typedef float v4f __attribute__((ext_vector_type(4)));   // 4 f32 acc

// ---- NEW-path workspace byte offsets ----
#define NOFF_S     81920000UL
#define NOFF_XB   145920000UL
#define NOFF_IDX  186880000UL
#define NOFF_VALS 190080000UL
#define NOFF_I10  193280000UL
#define NOFF_RES  194880000UL
#define NEED_NEW  195200000UL

// ---- OLD-path (fallback) offsets ----
#define OOFF_IDX16 81920000UL
#define OOFF_VALSD 84480000UL
#define OOFF_IDX10 87680000UL
#define OOFF_RESD  89280000UL

static __device__ __forceinline__ unsigned short f2bf(float x) {
  unsigned u = __float_as_uint(x);
  unsigned r = (u + 0x7FFFu + ((u >> 16) & 1u)) >> 16;   // RNE; inputs have no NaN
  return (unsigned short)r;
}

// ---------------------------------------------------------------------------
// K1: gather Xs[q][m][:] = X[ranks[m][q]][:]  (f32) + bf16 copy for MFMA screen
// ---------------------------------------------------------------------------
__global__ void k_gather(const float* __restrict__ X, const int* __restrict__ ranks,
                         float* __restrict__ Xs, unsigned short* __restrict__ Xsb,
                         int make_bf) {
  int gid = blockIdx.x * 256 + threadIdx.x;        // 5,120,000 threads exactly
  int c4  = gid & 127;
  int row = gid >> 7;                              // q*MM + m
  int q   = row / MM;
  int m   = row - q * MM;
  int id  = ranks[m * NQ + q];
  float4 v = ((const float4*)X)[(size_t)id * 128 + c4];
  ((float4*)Xs)[(size_t)row * 128 + c4] = v;
  if (make_bf) {
    ushort4 h;
    h.x = f2bf(v.x); h.y = f2bf(v.y); h.z = f2bf(v.z); h.w = f2bf(v.w);
    ((ushort4*)Xsb)[(size_t)row * 128 + c4] = h;
  }
}

// ---------------------------------------------------------------------------
// K2: bf16 MFMA screening GEMM  S = Xs Xs^T per query, S materialized f32.
// ---------------------------------------------------------------------------
#define LDB 40
__launch_bounds__(256)
__global__ void k_gemm(const unsigned short* __restrict__ Xsb, float* __restrict__ S) {
  __shared__ unsigned short As[128 * LDB];
  __shared__ unsigned short Bs[128 * LDB];

  const int q    = blockIdx.y;
  const int mt   = blockIdx.x >> 2;
  const int nt   = blockIdx.x & 3;
  const int m0   = mt * 128, n0 = nt * 128;
  const int tid  = threadIdx.x;
  const int wave = tid >> 6, lane = tid & 63;
  const int wr   = wave >> 1, wc = wave & 1;       // wave origin in block tile
  const int frow = lane & 15, quad = lane >> 4;

  const unsigned short* Xq = Xsb + (size_t)q * MM * DD;

  v4f acc[4][4];
  #pragma unroll
  for (int i = 0; i < 4; ++i)
    #pragma unroll
    for (int j = 0; j < 4; ++j)
      acc[i][j] = (v4f){0.f, 0.f, 0.f, 0.f};

  const int sr = tid >> 1;                 // staging row 0..127
  const int sk = (tid & 1) * 16;           // staging k-half

  for (int kc = 0; kc < DD; kc += 32) {
    __syncthreads();
    {  // stage A rows (m-block)
      int mrow = m0 + sr; if (mrow > MM - 1) mrow = MM - 1;
      const unsigned short* src = Xq + (size_t)mrow * DD + kc + sk;
      v8s t0 = *(const v8s*)(src);
      v8s t1 = *(const v8s*)(src + 8);
      *(v8s*)&As[sr * LDB + sk]     = t0;
      *(v8s*)&As[sr * LDB + sk + 8] = t1;
    }
    {  // stage B rows (n-block)
      int nrow = n0 + sr; if (nrow > MM - 1) nrow = MM - 1;
      const unsigned short* src = Xq + (size_t)nrow * DD + kc + sk;
      v8s t0 = *(const v8s*)(src);
      v8s t1 = *(const v8s*)(src + 8);
      *(v8s*)&Bs[sr * LDB + sk]     = t0;
      *(v8s*)&Bs[sr * LDB + sk + 8] = t1;
    }
    __syncthreads();

    v8s a[4], b[4];
    #pragma unroll
    for (int i = 0; i < 4; ++i)
      a[i] = *(const v8s*)&As[(wr * 64 + i * 16 + frow) * LDB + quad * 8];
    #pragma unroll
    for (int j = 0; j < 4; ++j)
      b[j] = *(const v8s*)&Bs[(wc * 64 + j * 16 + frow) * LDB + quad * 8];
    #pragma unroll
    for (int i = 0; i < 4; ++i)
      #pragma unroll
      for (int j = 0; j < 4; ++j)
        acc[i][j] = __builtin_amdgcn_mfma_f32_16x16x32_bf16(a[i], b[j], acc[i][j], 0, 0, 0);
  }

  // epilogue: C layout col=lane&15, row=quad*4+reg  [m89-verified]
  #pragma unroll
  for (int j = 0; j < 4; ++j) {
    int n = n0 + wc * 64 + j * 16 + frow;
    if (n >= MM) continue;
    #pragma unroll
    for (int i = 0; i < 4; ++i) {
      #pragma unroll
      for (int r = 0; r < 4; ++r) {
        int m = m0 + wr * 64 + i * 16 + quad * 4 + r;
        if (m < MM) S[((size_t)q * MM + m) * MM + n] = acc[i][j][r];
      }
    }
  }
}

// ---------------------------------------------------------------------------
// K3 fused (round-9): 2-BIT radix-ballot selection (16 serial passes, 3
// independent counts each — half the chain depth of round 8) + CHUNKED
// batched f64 reductions in phase 2 (butterfly stages shared across 5
// candidates — chain depth per chunk ~1 butterfly instead of 5).
//   - T exact: each 2-bit pass == two 1-bit binary-search steps.
//   - per-dot butterfly stage order unchanged -> sv bit-identical to round 8.
//   - a[] stored f32, promoted at use (exact; round-7-verified).
//   - rank / dba / res_top numerics bit-identical to round 8.
//   - XCD-chunked block->row map keeps each query's rows on one XCD.
// ---------------------------------------------------------------------------
__launch_bounds__(256)
__global__ void k_srdba(const float* __restrict__ Xs, const float* __restrict__ Q,
                        const float* __restrict__ S,
                        float* __restrict__ out_x, float* __restrict__ out_rt,
                        double* __restrict__ resd) {
  const int wv   = threadIdx.x >> 6;
  const int lane = threadIdx.x & 63;
  const int b    = blockIdx.x;
  const int cb   = (b & 7) * 1250 + (b >> 3);    // 10000 = 8*1250, bijective
  const int row  = cb * 4 + wv;                  // 400 % 4 == 0: no q-crossing
  const int q    = row / MM;
  const int m    = row - q * MM;
  const float* Xq = Xs + (size_t)q * MM * DD;
  const float* Sr = S  + (size_t)row * MM;

  // own descriptor, f32 storage (promotion to f64 at use is exact)
  float a[8];
  {
    const float* ar = Xq + (size_t)m * DD + lane * 8;
    float4 a0 = *(const float4*)(ar);
    float4 a1 = *(const float4*)(ar + 4);
    a[0]=a0.x; a[1]=a0.y; a[2]=a0.z; a[3]=a0.w;
    a[4]=a1.x; a[5]=a1.y; a[6]=a1.z; a[7]=a1.w;
  }

  // monotone u32 keys over the S row
  unsigned kv[7];
  #pragma unroll
  for (int s = 0; s < 7; ++s) {
    int n = lane + 64 * s;
    if (n < MM) {
      unsigned u = __float_as_uint(Sr[n]);
      kv[s] = u ^ ((u >> 31) ? 0xFFFFFFFFu : 0x80000000u);   // monotone map
    } else {
      kv[s] = 0u;                                            // below all real keys
    }
  }

  __shared__ double   sv[4][NS];
  __shared__ int      si[4][NS];
  __shared__ double   tv[4][KK];
  __shared__ int      ti[4][KK];
  __shared__ unsigned lv[4][64];
  __shared__ int      li[4][64];

  // ---- PHASE 1a: T = NS-th largest key; 2 bits per pass (16 serial passes,
  //      3 independent counts per pass == two binary-search steps) ----
  unsigned prefix = 0u;
  #pragma unroll
  for (int bit = 30; bit >= 0; bit -= 2) {
    unsigned c1 = prefix | (1u << bit);
    unsigned c2 = prefix | (2u << bit);
    unsigned c3 = prefix | (3u << bit);
    int n1 = 0, n2 = 0, n3 = 0;
    #pragma unroll
    for (int s = 0; s < 7; ++s) {
      n1 += (int)__popcll(__ballot(kv[s] >= c1));
      n2 += (int)__popcll(__ballot(kv[s] >= c2));
      n3 += (int)__popcll(__ballot(kv[s] >= c3));
    }
    prefix = (n3 >= NS) ? c3 : (n2 >= NS) ? c2 : (n1 >= NS) ? c1 : prefix;
  }
  // prefix == T: the NS-th largest key (exact)

  // ---- PHASE 1b: ballot-compact entries >= T (C in [NS, 64], asc index) ----
  int base = 0;
  #pragma unroll
  for (int s = 0; s < 7; ++s) {
    bool p = (kv[s] >= prefix);
    unsigned long long mk = __ballot(p);
    if (p) {
      unsigned lo = (unsigned)(mk & 0xFFFFFFFFull);
      unsigned hi = (unsigned)(mk >> 32);
      int pos = base + (int)__builtin_amdgcn_mbcnt_hi(hi,
                          __builtin_amdgcn_mbcnt_lo(lo, 0u));
      if (pos < 64) { lv[wv][pos] = kv[s]; li[wv][pos] = lane + 64 * s; }
    }
    base += (int)__popcll(mk);
  }
  int C = (base < 64) ? base : 64;          // clamp (pathological ties only)
  __syncthreads();

  // ---- PHASE 1c: rank among C entries; si[rank] = index (lax.top_k order) ----
  if (lane < C) {
    unsigned v = lv[wv][lane]; int n = li[wv][lane];
    int rank = 0;
    for (int i = 0; i < C; ++i)
      rank += (lv[wv][i] > v) || (lv[wv][i] == v && li[wv][i] < n);
    if (rank < NS) si[wv][rank] = n;
  }
  __syncthreads();

  // ---- PHASE 2: refine dots; chunks of 5 with BATCHED butterfly stages.
  //      Per-dot stage order identical to before -> bit-identical sv. ----
  #pragma unroll
  for (int c0 = 0; c0 < NS; c0 += 5) {
    double dp[5];
    #pragma unroll
    for (int t = 0; t < 5; ++t) {
      int n = si[wv][c0 + t];                  // uniform LDS broadcast
      const float* br = Xq + (size_t)n * DD + lane * 8;
      float4 b0 = *(const float4*)(br);
      float4 b1 = *(const float4*)(br + 4);
      dp[t] = (double)a[0]*(double)b0.x + (double)a[1]*(double)b0.y
            + (double)a[2]*(double)b0.z + (double)a[3]*(double)b0.w
            + (double)a[4]*(double)b1.x + (double)a[5]*(double)b1.y
            + (double)a[6]*(double)b1.z + (double)a[7]*(double)b1.w;
    }
    #pragma unroll
    for (int off = 32; off; off >>= 1) {
      #pragma unroll
      for (int t = 0; t < 5; ++t)
        dp[t] += __shfl_xor(dp[t], off);       // 5 independent shuffles/stage
    }
    if (lane == 0) {
      #pragma unroll
      for (int t = 0; t < 5; ++t) sv[wv][c0 + t] = dp[t];
    }
  }
  __syncthreads();

  // exact rank among the NS refined values (value desc, index asc — lax.top_k)
  if (lane < NS) {
    double v = sv[wv][lane]; int n = si[wv][lane];
    int rank = 0;
    #pragma unroll
    for (int i = 0; i < NS; ++i)
      rank += (sv[wv][i] > v) || (sv[wv][i] == v && si[wv][i] < n);
    if (rank < KK) { tv[wv][rank] = v; ti[wv][rank] = n; }
  }
  __syncthreads();

  // dba: top-10 rows just read by this wave -> L1/L2 hot. Same accumulation
  // order and /denom as round 8.
  double acc[8] = {0,0,0,0,0,0,0,0};
  double denom = 0.0;
  #pragma unroll
  for (int k = 0; k < KK; ++k) {
    double vv = tv[wv][k];
    double wk = (k == 0) ? 1.0 : 0.15 * vv;
    denom += wk;
    const float* gr = Xq + (size_t)ti[wv][k] * DD + lane * 8;
    float4 g0 = *(const float4*)(gr);
    float4 g1 = *(const float4*)(gr + 4);
    acc[0] += wk * (double)g0.x; acc[1] += wk * (double)g0.y;
    acc[2] += wk * (double)g0.z; acc[3] += wk * (double)g0.w;
    acc[4] += wk * (double)g1.x; acc[5] += wk * (double)g1.y;
    acc[6] += wk * (double)g1.z; acc[7] += wk * (double)g1.w;
  }
  double x[8];
  #pragma unroll
  for (int e = 0; e < 8; ++e) x[e] = acc[e] / denom;

  float* ox = out_x + (size_t)row * DD + lane * 8;
  *(float4*)(ox)     = make_float4((float)x[0], (float)x[1], (float)x[2], (float)x[3]);
  *(float4*)(ox + 4) = make_float4((float)x[4], (float)x[5], (float)x[6], (float)x[7]);

  const float* Qr = Q + (size_t)q * DD + lane * 8;
  float4 q0 = *(const float4*)(Qr);
  float4 q1 = *(const float4*)(Qr + 4);
  double pp = x[0]*(double)q0.x + x[1]*(double)q0.y + x[2]*(double)q0.z + x[3]*(double)q0.w
            + x[4]*(double)q1.x + x[5]*(double)q1.y + x[6]*(double)q1.z + x[7]*(double)q1.w;
  #pragma unroll
  for (int off = 32; off; off >>= 1) pp += __shfl_xor(pp, off);
  if (lane == 0) { resd[row] = pp; out_rt[row] = (float)pp; }
}

// ---------------------------------------------------------------------------
// OLD K2 (fallback if ws too small): f32 tile GEMM + fused top-16
// ---------------------------------------------------------------------------
#define TM 32
#define TN 128
#define KC 16
__launch_bounds__(256, 2)
__global__ void k_score_top16(const float* __restrict__ Xs, int* __restrict__ idx16) {
  __shared__ float As_[KC][TM];
  __shared__ float Bs_[KC][TN];
  __shared__ float Cs_[TM][408];
  const int q   = blockIdx.y;
  const int m0  = blockIdx.x * TM;
  const int tid = threadIdx.x;
  const int tr  = tid & 7;
  const int tc  = tid >> 3;
  const float* Xq = Xs + (size_t)q * MM * DD;
  for (int nt = 0; nt < 4; ++nt) {
    const int n0 = nt * TN;
    float acc[4][4] = {{0.f,0.f,0.f,0.f},{0.f,0.f,0.f,0.f},
                       {0.f,0.f,0.f,0.f},{0.f,0.f,0.f,0.f}};
    for (int kc = 0; kc < DD; kc += KC) {
      __syncthreads();
      { int r = tid >> 3; int cc = (tid & 7) * 2;
        int mrow = m0 + r; if (mrow > MM - 1) mrow = MM - 1;
        float2 a = *(const float2*)(Xq + (size_t)mrow * DD + kc + cc);
        As_[cc + 0][r] = a.x; As_[cc + 1][r] = a.y; }
      { int r = tid >> 1; int cc = (tid & 1) * 8;
        int nrow = n0 + r; if (nrow > MM - 1) nrow = MM - 1;
        const float* src = Xq + (size_t)nrow * DD + kc + cc;
        #pragma unroll
        for (int j = 0; j < 2; ++j) {
          float4 b = *(const float4*)(src + 4 * j);
          Bs_[cc + 4*j + 0][r] = b.x; Bs_[cc + 4*j + 1][r] = b.y;
          Bs_[cc + 4*j + 2][r] = b.z; Bs_[cc + 4*j + 3][r] = b.w; } }
      __syncthreads();
      #pragma unroll
      for (int k = 0; k < KC; ++k) {
        float4 a4 = *(const float4*)&As_[k][tr * 4];
        float4 b4 = *(const float4*)&Bs_[k][tc * 4];
        float av[4] = {a4.x, a4.y, a4.z, a4.w};
        float bw[4] = {b4.x, b4.y, b4.z, b4.w};
        #pragma unroll
        for (int i = 0; i < 4; ++i)
          #pragma unroll
          for (int j = 0; j < 4; ++j)
            acc[i][j] = fmaf(av[i], bw[j], acc[i][j]);
      }
    }
    #pragma unroll
    for (int i = 0; i < 4; ++i) {
      int r = tr * 4 + i;
      #pragma unroll
      for (int j = 0; j < 4; ++j) {
        int col = n0 + tc * 4 + j;
        if (col < MM) Cs_[r][col] = acc[i][j];
      }
    }
  }
  __syncthreads();
  const int lane = tid & 63;
  const int wv   = tid >> 6;
  for (int r = wv; r < TM; r += 4) {
    const int m = m0 + r;
    if (m >= MM) continue;
    float v[7]; int nn[7];
    #pragma unroll
    for (int s = 0; s < 7; ++s) {
      int n = lane + 64 * s;
      bool ok = (n < MM);
      v[s]  = ok ? Cs_[r][n] : -INFINITY;
      nn[s] = ok ? n : 0x7fffffff;
    }
    for (int t = 0; t < 16; ++t) {
      float bv = v[0]; int bn = nn[0];
      #pragma unroll
      for (int s = 1; s < 7; ++s)
        if (v[s] > bv || (v[s] == bv && nn[s] < bn)) { bv = v[s]; bn = nn[s]; }
      for (int off = 32; off; off >>= 1) {
        float ov = __shfl_xor(bv, off);
        int   on = __shfl_xor(bn, off);
        if (ov > bv || (ov == bv && on < bn)) { bv = ov; bn = on; }
      }
      if (lane == 0) idx16[((size_t)q * MM + m) * 16 + t] = bn;
      #pragma unroll
      for (int s = 0; s < 7; ++s)
        if (nn[s] == bn) v[s] = -INFINITY;
    }
  }
}

// ---------------------------------------------------------------------------
// OLD K3: refine (fallback path)
// ---------------------------------------------------------------------------
__global__ void k_refine(const float* __restrict__ Xs, const int* __restrict__ idxbuf,
                         int ns, double* __restrict__ valsd, int* __restrict__ idx10) {
  const int row  = blockIdx.x;           // q*MM + m
  const int q    = row / MM;
  const int m    = row - q * MM;
  const int lane = threadIdx.x;          // 64
  const float* Xq = Xs + (size_t)q * MM * DD;

  double a[8];
  {
    const float* ar = Xq + (size_t)m * DD + lane * 8;
    float4 a0 = *(const float4*)(ar);
    float4 a1 = *(const float4*)(ar + 4);
    a[0]=a0.x; a[1]=a0.y; a[2]=a0.z; a[3]=a0.w;
    a[4]=a1.x; a[5]=a1.y; a[6]=a1.z; a[7]=a1.w;
  }
  __shared__ double sv[24];
  __shared__ int    si[24];
  for (int j = 0; j < ns; ++j) {
    int n = idxbuf[(size_t)row * ns + j];
    const float* br = Xq + (size_t)n * DD + lane * 8;
    float4 b0 = *(const float4*)(br);
    float4 b1 = *(const float4*)(br + 4);
    double s = a[0]*(double)b0.x + a[1]*(double)b0.y + a[2]*(double)b0.z + a[3]*(double)b0.w
             + a[4]*(double)b1.x + a[5]*(double)b1.y + a[6]*(double)b1.z + a[7]*(double)b1.w;
    for (int off = 32; off; off >>= 1) s += __shfl_xor(s, off);
    if (lane == 0) { sv[j] = s; si[j] = n; }
  }
  __syncthreads();
  if (lane < ns) {
    double v = sv[lane]; int n = si[lane];
    int rank = 0;
    for (int i = 0; i < ns; ++i)
      if (sv[i] > v || (sv[i] == v && si[i] < n)) ++rank;
    if (rank < KK) {
      valsd[(size_t)row * KK + rank] = v;
      idx10[(size_t)row * KK + rank] = n;
    }
  }
}

// ---------------------------------------------------------------------------
// OLD K4: x_dba + res_top (fallback path)
// ---------------------------------------------------------------------------
__global__ void k_dba(const float* __restrict__ Xs, const float* __restrict__ Q,
                      const double* __restrict__ valsd, const int* __restrict__ idx10,
                      float* __restrict__ out_x, float* __restrict__ out_rt,
                      double* __restrict__ resd) {
  const int row = blockIdx.x;            // q*MM + m
  const int q   = row / MM;
  const int tid = threadIdx.x;           // 128
  const float* Xq = Xs + (size_t)q * MM * DD;

  double w[KK]; int id[KK]; double denom = 0.0;
  #pragma unroll
  for (int k = 0; k < KK; ++k) {
    double vv = valsd[(size_t)row * KK + k];
    w[k] = (k == 0) ? 1.0 : 0.15 * vv;
    denom += w[k];
    id[k] = idx10[(size_t)row * KK + k];
  }
  double acc0 = 0, acc1 = 0, acc2 = 0, acc3 = 0;
  #pragma unroll
  for (int k = 0; k < KK; ++k) {
    float4 g = *(const float4*)(Xq + (size_t)id[k] * DD + tid * 4);
    acc0 += w[k] * (double)g.x;
    acc1 += w[k] * (double)g.y;
    acc2 += w[k] * (double)g.z;
    acc3 += w[k] * (double)g.w;
  }
  double x0 = acc0 / denom, x1 = acc1 / denom, x2 = acc2 / denom, x3 = acc3 / denom;
  ((float4*)out_x)[(size_t)row * 128 + tid] =
      make_float4((float)x0, (float)x1, (float)x2, (float)x3);

  const float* Qr = Q + (size_t)q * DD + tid * 4;
  double p = x0 * (double)Qr[0] + x1 * (double)Qr[1] + x2 * (double)Qr[2] + x3 * (double)Qr[3];
  for (int off = 32; off; off >>= 1) p += __shfl_xor(p, off);
  __shared__ double ps[2];
  if ((tid & 63) == 0) ps[tid >> 6] = p;
  __syncthreads();
  if (tid == 0) {
    double rt = ps[0] + ps[1];
    resd[row]   = rt;
    out_rt[row] = (float)rt;
  }
}

// ---------------------------------------------------------------------------
// K5: stable descending argsort of res_top (f64) per query → pre, rerank_final
// ---------------------------------------------------------------------------
__global__ void k_sort(const double* __restrict__ resd, const int* __restrict__ ranks,
                       float* __restrict__ out_rr, float* __restrict__ out_pre) {
  const int q   = blockIdx.x;
  const int tid = threadIdx.x;           // 512
  __shared__ double sv[MM];
  if (tid < MM) sv[tid] = resd[(size_t)q * MM + tid];
  __syncthreads();
  if (tid < MM) {
    double v = sv[tid];
    int rank = 0;
    for (int j = 0; j < MM; ++j) {
      double u = sv[j];
      rank += (u > v) || (u == v && j < tid);
    }
    out_pre[(size_t)q * MM + rank] = (float)tid;
    out_rr [(size_t)q * MM + rank] = (float)ranks[tid * NQ + q];
  }
}

// ---------------------------------------------------------------------------
extern "C" void kernel_launch(void* const* d_in, const int* in_sizes, int n_in,
                              void* d_out, int out_size, void* d_ws, size_t ws_size,
                              hipStream_t stream) {
  const float* X     = (const float*)d_in[0];
  const float* Q     = (const float*)d_in[1];
  const int*   ranks = (const int*)d_in[2];

  float* out    = (float*)d_out;
  float* out_rr = out;                   // rerank_final [100][400]
  float* out_rt = out + 40000;           // res_top      [100][400]
  float* out_pr = out + 80000;           // pre          [100][400]
  float* out_x  = out + 120000;          // x_dba        [100][400][512]

  float* Xs = (float*)d_ws;

  if (ws_size >= NEED_NEW) {
    float*          S     = (float*)          ((char*)d_ws + NOFF_S);
    unsigned short* Xsb   = (unsigned short*) ((char*)d_ws + NOFF_XB);
    double*         resd  = (double*)         ((char*)d_ws + NOFF_RES);

    k_gather<<<dim3(20000),   dim3(256), 0, stream>>>(X, ranks, Xs, Xsb, 1);
    k_gemm  <<<dim3(16, 100), dim3(256), 0, stream>>>(Xsb, S);
    k_srdba <<<dim3(10000),   dim3(256), 0, stream>>>(Xs, Q, S, out_x, out_rt, resd);
    k_sort  <<<dim3(100),     dim3(512), 0, stream>>>(resd, ranks, out_rr, out_pr);
  } else {
    int*    idx16 = (int*)   ((char*)d_ws + OOFF_IDX16);
    double* valsd = (double*)((char*)d_ws + OOFF_VALSD);
    int*    idx10 = (int*)   ((char*)d_ws + OOFF_IDX10);
    double* resd  = (double*)((char*)d_ws + OOFF_RESD);

    k_gather     <<<dim3(20000),   dim3(256), 0, stream>>>(X, ranks, Xs, (unsigned short*)0, 0);
    k_score_top16<<<dim3(13, 100), dim3(256), 0, stream>>>(Xs, idx16);
    k_refine     <<<dim3(40000),   dim3(64),  0, stream>>>(Xs, idx16, 16, valsd, idx10);
    k_dba        <<<dim3(40000),   dim3(128), 0, stream>>>(Xs, Q, valsd, idx10, out_x, out_rt, resd);
    k_sort       <<<dim3(100),     dim3(512), 0, stream>>>(resd, ranks, out_rr, out_pr);
  }
}